// Round 4
// baseline (134.121 us; speedup 1.0000x reference)
//
#include <hip/hip_runtime.h>
#include <stdint.h>

// Sizes: h (8,1024,512) f32, s (8,128,1024)->(1024,1024) f32,
//        Wh (512,128), Ws (1024,128), b,v (128,), out (8,128,1024) f32.
//
// Key identity: tanh(ps+ph) = 1 - 2/(Eps*Eph + 1),
//   Eps = exp2(2*log2e*ps), Eph = exp2(2*log2e*ph) precomputed in the GEMM
//   epilogue (1.18M exp2 instead of 134M in the attn loop).
// Attn inner op per element: fma(Eps,Eph,1) -> rcp -> fma(v,.,acc).
//
// Pipeline:
//   1. transpose_cast : WhT[a][c], WsT[a][d] bf16 (k-contiguous A operands)
//   2. gemm_fused     : barrier-free register MFMA GEMM; epilogue writes
//                       Eph[n][a][x], Eps[a][ny]
//   3. attn_softmax   : 4 y-rows/thread (halves Eph L2 re-reads vs 2y),
//                       e = Vsum - 2*sum_a v_a*rcp(Eps*Eph+1), fused softmax

typedef float  f32x4  __attribute__((ext_vector_type(4)));
typedef __bf16 bf16x8 __attribute__((ext_vector_type(8)));

#define LOG2E     1.4426950408889634f
#define TWO_LOG2E 2.8853900817779268f

// ------------------------------------------------- weight transpose + cast
__global__ void __launch_bounds__(256) transpose_cast(
    const float* __restrict__ Wh, const float* __restrict__ Ws,
    __bf16* __restrict__ WhT, __bf16* __restrict__ WsT)
{
    int bid = blockIdx.x;  // 0..7 -> Wh tiles, 8..23 -> Ws tiles
    const float* src; __bf16* dst; int K, c0;
    if (bid < 8) { src = Wh; dst = WhT; K = 512;  c0 = bid * 64; }
    else         { src = Ws; dst = WsT; K = 1024; c0 = (bid - 8) * 64; }
    __shared__ float tile[64][129];
    int t = threadIdx.x;
    for (int i = 0; i < 8192; i += 256) {
        int idx = i + t;
        int r = idx >> 7, col = idx & 127;              // 64 rows(c) x 128 cols(a)
        tile[r][col] = src[(size_t)(c0 + r) * 128 + col];
    }
    __syncthreads();
    for (int i = 0; i < 8192; i += 256) {
        int idx = i + t;
        int a = idx >> 6, cc = idx & 63;                // 128 rows(a) x 64 cols(c)
        dst[(size_t)a * K + c0 + cc] = (__bf16)tile[cc][a];
    }
}

// --------------------------------------- barrier-free register MFMA GEMM
// blocks 0..255 : Eph  (A=WhT 128x512,  B=h f32,  32 cols/block)
// blocks 256..287: Eps (A=WsT 128x1024, B=s f32,  32 cols/block, +bias)
// wave w: m-half = (w&1)*64 (4 m-tiles), col-group = (w>>1)*16.
__global__ void __launch_bounds__(256) gemm_fused(
    const __bf16* __restrict__ WhT, const __bf16* __restrict__ WsT,
    const float* __restrict__ h, const float* __restrict__ s,
    float* __restrict__ Eph, float* __restrict__ Eps,
    const float* __restrict__ bias)
{
    int bid = blockIdx.x;
    int tid = threadIdx.x, lane = tid & 63, w = tid >> 6;
    int mbase = (w & 1) * 64;
    const __bf16* A; const float* B; float* Cp; int K; bool isPs;
    int colg;
    if (bid < 256) {
        isPs = false; A = WhT; B = h; K = 512;
        colg = bid * 32 + (w >> 1) * 16;
        int n = colg >> 10, x = colg & 1023;
        Cp = Eph + (size_t)n * 131072 + x;     // + m*1024 + col in epilogue
    } else {
        isPs = true; A = WsT; B = s; K = 1024;
        colg = (bid - 256) * 32 + (w >> 1) * 16;
        Cp = Eps + colg;
    }
    int q = lane >> 4;
    const float*  Bp = B + (size_t)(colg + (lane & 15)) * K + q * 8;
    const __bf16* Ap = A + (size_t)(mbase + (lane & 15)) * K + q * 8;

    f32x4 acc[4] = {};
    float4 b0 = *(const float4*)(Bp);
    float4 b1 = *(const float4*)(Bp + 4);
    bf16x8 a_[4];
    #pragma unroll
    for (int i = 0; i < 4; ++i) a_[i] = *(const bf16x8*)(Ap + (size_t)i * 16 * K);

    for (int k0 = 0; k0 < K; k0 += 32) {
        int kn = k0 + 32; if (kn > K - 32) kn = K - 32;   // clamped (dup last)
        float4 nb0 = *(const float4*)(Bp + kn);
        float4 nb1 = *(const float4*)(Bp + kn + 4);
        bf16x8 na[4];
        #pragma unroll
        for (int i = 0; i < 4; ++i)
            na[i] = *(const bf16x8*)(Ap + (size_t)i * 16 * K + kn);
        bf16x8 bf;
        bf[0] = (__bf16)b0.x; bf[1] = (__bf16)b0.y;
        bf[2] = (__bf16)b0.z; bf[3] = (__bf16)b0.w;
        bf[4] = (__bf16)b1.x; bf[5] = (__bf16)b1.y;
        bf[6] = (__bf16)b1.z; bf[7] = (__bf16)b1.w;
        #pragma unroll
        for (int i = 0; i < 4; ++i)
            acc[i] = __builtin_amdgcn_mfma_f32_16x16x32_bf16(a_[i], bf, acc[i], 0, 0, 0);
        b0 = nb0; b1 = nb1;
        #pragma unroll
        for (int i = 0; i < 4; ++i) a_[i] = na[i];
    }

    // C/D layout: col=lane&15, row(within 16-tile)=q*4+r  (m89-verified)
    int col = lane & 15;
    #pragma unroll
    for (int i = 0; i < 4; ++i) {
        #pragma unroll
        for (int r = 0; r < 4; ++r) {
            int m = mbase + i * 16 + q * 4 + r;
            float vv = acc[i][r];
            if (isPs) vv += bias[m];
            Cp[(size_t)m * 1024 + col] =
                __builtin_amdgcn_exp2f(vv * TWO_LOG2E);
        }
    }
}

// ------------------------------------------- fused tanh-dot + softmax
// block = (n, y-quad), 512 threads; thread t owns x = {2t, 2t+1}, 4 y-rows.
// e = Vsum - 2 * sum_a v_a * rcp(fma(Eps, Eph, 1))
__global__ void __launch_bounds__(512) attn_softmax(
    const float* __restrict__ Eph, const float* __restrict__ Eps,
    const float* __restrict__ v, float* __restrict__ out)
{
    int bid = blockIdx.x;            // 256 blocks = n(8) x yg(32)
    int n = bid >> 5, yg = bid & 31;
    int ny = n * 128 + yg * 4;       // 4 consecutive global rows
    const float2* ph2 = (const float2*)(Eph + (size_t)n * 131072);
    int t = threadIdx.x;

    __shared__ float4 ps_s[128];     // Eps[a][ny..ny+3]
    __shared__ float  v_s[128];
    __shared__ float  wred[4][8];
    __shared__ float  VsumS;

    if (t < 128) {
        ps_s[t] = *(const float4*)(Eps + (size_t)t * 1024 + ny);
        v_s[t]  = v[t];
    } else if (t < 192) {            // second wave computes Vsum
        int l = t - 128;
        float vv = v[l] + v[l + 64];
        for (int m = 32; m; m >>= 1) vv += __shfl_xor(vv, m);
        if (l == 0) VsumS = vv;
    }
    __syncthreads();
    float Vsum = VsumS;

    float acc0[4] = {0, 0, 0, 0}, acc1[4] = {0, 0, 0, 0};
    #pragma unroll 4
    for (int a = 0; a < 128; ++a) {
        float4 ps4 = ps_s[a];                // broadcast ds_read_b128
        float  va  = v_s[a];                 // broadcast ds_read_b32
        float2 p2  = ph2[a * 512 + t];       // coalesced float2 (L2/L3)
        float psy[4] = {ps4.x, ps4.y, ps4.z, ps4.w};
        #pragma unroll
        for (int y = 0; y < 4; ++y) {
            float z0 = fmaf(psy[y], p2.x, 1.f);
            float z1 = fmaf(psy[y], p2.y, 1.f);
            acc0[y] = fmaf(va, __builtin_amdgcn_rcpf(z0), acc0[y]);
            acc1[y] = fmaf(va, __builtin_amdgcn_rcpf(z1), acc1[y]);
        }
    }

    float e0[4], e1[4];
    #pragma unroll
    for (int y = 0; y < 4; ++y) {
        e0[y] = fmaf(-2.f, acc0[y], Vsum);
        e1[y] = fmaf(-2.f, acc1[y], Vsum);
    }

    int lane = t & 63, wv = t >> 6;
    // block max per y (8 waves)
    #pragma unroll
    for (int y = 0; y < 4; ++y) {
        float mx = fmaxf(e0[y], e1[y]);
        for (int m = 32; m; m >>= 1) mx = fmaxf(mx, __shfl_xor(mx, m));
        if (lane == 0) wred[y][wv] = mx;
    }
    __syncthreads();
    float mxv[4];
    #pragma unroll
    for (int y = 0; y < 4; ++y) {
        float mx = wred[y][0];
        #pragma unroll
        for (int i = 1; i < 8; ++i) mx = fmaxf(mx, wred[y][i]);
        mxv[y] = mx;
    }
    __syncthreads();
    // exp + block sum per y
    float s0[4], s1[4], smv[4];
    #pragma unroll
    for (int y = 0; y < 4; ++y) {
        s0[y] = __builtin_amdgcn_exp2f((e0[y] - mxv[y]) * LOG2E);
        s1[y] = __builtin_amdgcn_exp2f((e1[y] - mxv[y]) * LOG2E);
        float sm = s0[y] + s1[y];
        for (int m = 32; m; m >>= 1) sm += __shfl_xor(sm, m);
        if (lane == 0) wred[y][wv] = sm;
    }
    __syncthreads();
    #pragma unroll
    for (int y = 0; y < 4; ++y) {
        float sm = 0.f;
        #pragma unroll
        for (int i = 0; i < 8; ++i) sm += wred[y][i];
        smv[y] = __builtin_amdgcn_rcpf(sm);
    }
    #pragma unroll
    for (int y = 0; y < 4; ++y) {
        float2 o; o.x = s0[y] * smv[y]; o.y = s1[y] * smv[y];
        ((float2*)(out + (size_t)(ny + y) * 1024))[t] = o;
    }
}

// ----------------------------------------------------------------- launcher
extern "C" void kernel_launch(void* const* d_in, const int* in_sizes, int n_in,
                              void* d_out, int out_size, void* d_ws, size_t ws_size,
                              hipStream_t stream) {
    const float* h  = (const float*)d_in[0];
    const float* s  = (const float*)d_in[1];
    const float* Wh = (const float*)d_in[2];
    const float* Ws = (const float*)d_in[3];
    const float* b  = (const float*)d_in[4];
    const float* v  = (const float*)d_in[5];
    float* out = (float*)d_out;

    char* ws = (char*)d_ws;
    float*  Eph = (float*)ws;                                  // 4 MB
    float*  Eps = (float*)(ws + (4u << 20));                   // 512 KB
    __bf16* WhT = (__bf16*)(ws + (4u << 20) + (512u << 10));   // 128 KB
    __bf16* WsT = WhT + (size_t)128 * 512;                     // 256 KB

    transpose_cast<<<24, 256, 0, stream>>>(Wh, Ws, WhT, WsT);
    gemm_fused<<<288, 256, 0, stream>>>(WhT, WsT, h, s, Eph, Eps, b);
    attn_softmax<<<256, 512, 0, stream>>>(Eph, Eps, v, out);
}

// Round 5
// 129.356 us; speedup vs baseline: 1.0368x; 1.0368x over previous
//
#include <hip/hip_runtime.h>
#include <stdint.h>

// Sizes: h (8,1024,512) f32, s (8,128,1024)->(1024,1024) f32,
//        Wh (512,128), Ws (1024,128), b,v (128,), out (8,128,1024) f32.
//
// Identity 1: tanh(ps+ph) = 1 - 2/(Eps*Eph + 1),
//   Eps = exp2(2*log2e*ps), Eph = exp2(2*log2e*ph) precomputed in GEMM
//   epilogue (1.18M exp2 instead of 134M in the attn loop).
// Identity 2 (this round): sum_a v_a/w_a over 4 terms shares ONE rcp:
//   n01 = v0*w1 + v1*w0, d01 = w0*w1, merged pairwise -> 14 VALU + 1 rcp
//   per 4 reduction terms (was 8 VALU + 4 rcp). rcp is the expensive
//   wave64 trans op (8 issue-cyc), so this cuts attn issue ~25%.
//
// Pipeline:
//   1. transpose_cast : WhT[a][c], WsT[a][d] bf16 (k-contiguous A operands)
//   2. gemm_fused     : barrier-free register MFMA GEMM; epilogue writes
//                       Eph[n][a][x], Eps[a][ny]
//   3. attn_softmax   : 512 blocks x 512 thr (R3 shape — best measured),
//                       2y x 2x per thread, 4-term rcp sharing.

typedef float  f32x4  __attribute__((ext_vector_type(4)));
typedef __bf16 bf16x8 __attribute__((ext_vector_type(8)));

#define LOG2E     1.4426950408889634f
#define TWO_LOG2E 2.8853900817779268f

// ------------------------------------------------- weight transpose + cast
__global__ void __launch_bounds__(256) transpose_cast(
    const float* __restrict__ Wh, const float* __restrict__ Ws,
    __bf16* __restrict__ WhT, __bf16* __restrict__ WsT)
{
    int bid = blockIdx.x;  // 0..7 -> Wh tiles, 8..23 -> Ws tiles
    const float* src; __bf16* dst; int K, c0;
    if (bid < 8) { src = Wh; dst = WhT; K = 512;  c0 = bid * 64; }
    else         { src = Ws; dst = WsT; K = 1024; c0 = (bid - 8) * 64; }
    __shared__ float tile[64][129];
    int t = threadIdx.x;
    for (int i = 0; i < 8192; i += 256) {
        int idx = i + t;
        int r = idx >> 7, col = idx & 127;              // 64 rows(c) x 128 cols(a)
        tile[r][col] = src[(size_t)(c0 + r) * 128 + col];
    }
    __syncthreads();
    for (int i = 0; i < 8192; i += 256) {
        int idx = i + t;
        int a = idx >> 6, cc = idx & 63;                // 128 rows(a) x 64 cols(c)
        dst[(size_t)a * K + c0 + cc] = (__bf16)tile[cc][a];
    }
}

// --------------------------------------- barrier-free register MFMA GEMM
// blocks 0..255 : Eph  (A=WhT 128x512,  B=h f32,  32 cols/block)
// blocks 256..287: Eps (A=WsT 128x1024, B=s f32,  32 cols/block, +bias)
// wave w: m-half = (w&1)*64 (4 m-tiles), col-group = (w>>1)*16.
__global__ void __launch_bounds__(256) gemm_fused(
    const __bf16* __restrict__ WhT, const __bf16* __restrict__ WsT,
    const float* __restrict__ h, const float* __restrict__ s,
    float* __restrict__ Eph, float* __restrict__ Eps,
    const float* __restrict__ bias)
{
    int bid = blockIdx.x;
    int tid = threadIdx.x, lane = tid & 63, w = tid >> 6;
    int mbase = (w & 1) * 64;
    const __bf16* A; const float* B; float* Cp; int K; bool isPs;
    int colg;
    if (bid < 256) {
        isPs = false; A = WhT; B = h; K = 512;
        colg = bid * 32 + (w >> 1) * 16;
        int n = colg >> 10, x = colg & 1023;
        Cp = Eph + (size_t)n * 131072 + x;     // + m*1024 + col in epilogue
    } else {
        isPs = true; A = WsT; B = s; K = 1024;
        colg = (bid - 256) * 32 + (w >> 1) * 16;
        Cp = Eps + colg;
    }
    int q = lane >> 4;
    const float*  Bp = B + (size_t)(colg + (lane & 15)) * K + q * 8;
    const __bf16* Ap = A + (size_t)(mbase + (lane & 15)) * K + q * 8;

    f32x4 acc[4] = {};
    float4 b0 = *(const float4*)(Bp);
    float4 b1 = *(const float4*)(Bp + 4);
    bf16x8 a_[4];
    #pragma unroll
    for (int i = 0; i < 4; ++i) a_[i] = *(const bf16x8*)(Ap + (size_t)i * 16 * K);

    for (int k0 = 0; k0 < K; k0 += 32) {
        int kn = k0 + 32; if (kn > K - 32) kn = K - 32;   // clamped (dup last)
        float4 nb0 = *(const float4*)(Bp + kn);
        float4 nb1 = *(const float4*)(Bp + kn + 4);
        bf16x8 na[4];
        #pragma unroll
        for (int i = 0; i < 4; ++i)
            na[i] = *(const bf16x8*)(Ap + (size_t)i * 16 * K + kn);
        bf16x8 bf;
        bf[0] = (__bf16)b0.x; bf[1] = (__bf16)b0.y;
        bf[2] = (__bf16)b0.z; bf[3] = (__bf16)b0.w;
        bf[4] = (__bf16)b1.x; bf[5] = (__bf16)b1.y;
        bf[6] = (__bf16)b1.z; bf[7] = (__bf16)b1.w;
        #pragma unroll
        for (int i = 0; i < 4; ++i)
            acc[i] = __builtin_amdgcn_mfma_f32_16x16x32_bf16(a_[i], bf, acc[i], 0, 0, 0);
        b0 = nb0; b1 = nb1;
        #pragma unroll
        for (int i = 0; i < 4; ++i) a_[i] = na[i];
    }

    // C/D layout: col=lane&15, row(within 16-tile)=q*4+r  (m89-verified)
    int col = lane & 15;
    #pragma unroll
    for (int i = 0; i < 4; ++i) {
        #pragma unroll
        for (int r = 0; r < 4; ++r) {
            int m = mbase + i * 16 + q * 4 + r;
            float vv = acc[i][r];
            if (isPs) vv += bias[m];
            Cp[(size_t)m * 1024 + col] =
                __builtin_amdgcn_exp2f(vv * TWO_LOG2E);
        }
    }
}

// ------------------------------------------- fused tanh-dot + softmax
// block = (n, y-pair), 512 threads; thread t owns x = {2t, 2t+1}, 2 y-rows.
// acc[y][xi] = sum_a v_a * rcp(w_a),  w_a = fma(Eps_y[a], Eph[a][x], 1)
// computed 4 a-terms per rcp via rational-sum merging.
__global__ void __launch_bounds__(512) attn_softmax(
    const float* __restrict__ Eph, const float* __restrict__ Eps,
    const float* __restrict__ v, float* __restrict__ out)
{
    int bid = blockIdx.x;            // 512 blocks = n(8) x yg(64)
    int n = bid >> 6, yg = bid & 63;
    int ny = n * 128 + yg * 2;       // 2 consecutive global rows
    const float2* ph2 = (const float2*)(Eph + (size_t)n * 131072);
    int t = threadIdx.x;

    __shared__ float4 pv_s[128];     // {Eps[y0][a], Eps[y1][a], v[a], 0}
    __shared__ float wred[2][8];
    __shared__ float VsumS;

    if (t < 128) {
        float2 p = *(const float2*)(Eps + (size_t)t * 1024 + ny);
        float4 pk; pk.x = p.x; pk.y = p.y; pk.z = v[t]; pk.w = 0.f;
        pv_s[t] = pk;
    }
    if (t >= 448) {                  // last wave computes Vsum (disjoint)
        int l = t - 448;
        float vv = v[l] + v[l + 64];
        for (int m = 32; m; m >>= 1) vv += __shfl_xor(vv, m);
        if (l == 0) VsumS = vv;
    }
    __syncthreads();
    float Vsum = VsumS;

    float acc00 = 0.f, acc01 = 0.f, acc10 = 0.f, acc11 = 0.f;
    #pragma unroll 2
    for (int a = 0; a < 128; a += 4) {
        float4 q0 = pv_s[a + 0], q1 = pv_s[a + 1];
        float4 q2 = pv_s[a + 2], q3 = pv_s[a + 3];
        float2 p0 = ph2[(a + 0) * 512 + t];
        float2 p1 = ph2[(a + 1) * 512 + t];
        float2 p2 = ph2[(a + 2) * 512 + t];
        float2 p3 = ph2[(a + 3) * 512 + t];
        // one output (y fixed via eps args, x fixed via ph args):
        // 4-term rational sum: 14 VALU + 1 rcp
        auto comb = [&](float e0, float e1, float e2, float e3,
                        float h0, float h1, float h2, float h3, float& acc) {
            float w0 = fmaf(e0, h0, 1.f);
            float w1 = fmaf(e1, h1, 1.f);
            float w2 = fmaf(e2, h2, 1.f);
            float w3 = fmaf(e3, h3, 1.f);
            float d01 = w0 * w1, d23 = w2 * w3;
            float n01 = fmaf(q1.z, w0, q0.z * w1);
            float n23 = fmaf(q3.z, w2, q2.z * w3);
            float dd = d01 * d23;
            float nn = fmaf(n23, d01, n01 * d23);
            acc = fmaf(nn, __builtin_amdgcn_rcpf(dd), acc);
        };
        comb(q0.x, q1.x, q2.x, q3.x, p0.x, p1.x, p2.x, p3.x, acc00);
        comb(q0.x, q1.x, q2.x, q3.x, p0.y, p1.y, p2.y, p3.y, acc01);
        comb(q0.y, q1.y, q2.y, q3.y, p0.x, p1.x, p2.x, p3.x, acc10);
        comb(q0.y, q1.y, q2.y, q3.y, p0.y, p1.y, p2.y, p3.y, acc11);
    }
    float e00 = fmaf(-2.f, acc00, Vsum);
    float e01 = fmaf(-2.f, acc01, Vsum);
    float e10 = fmaf(-2.f, acc10, Vsum);
    float e11 = fmaf(-2.f, acc11, Vsum);

    int lane = t & 63, wv = t >> 6;
    float mx0 = fmaxf(e00, e01), mx1 = fmaxf(e10, e11);
    for (int m = 32; m; m >>= 1) {
        mx0 = fmaxf(mx0, __shfl_xor(mx0, m));
        mx1 = fmaxf(mx1, __shfl_xor(mx1, m));
    }
    if (lane == 0) { wred[0][wv] = mx0; wred[1][wv] = mx1; }
    __syncthreads();
    mx0 = wred[0][0]; mx1 = wred[1][0];
    #pragma unroll
    for (int i = 1; i < 8; ++i) {
        mx0 = fmaxf(mx0, wred[0][i]);
        mx1 = fmaxf(mx1, wred[1][i]);
    }
    __syncthreads();
    float s00 = __builtin_amdgcn_exp2f((e00 - mx0) * LOG2E);
    float s01 = __builtin_amdgcn_exp2f((e01 - mx0) * LOG2E);
    float s10 = __builtin_amdgcn_exp2f((e10 - mx1) * LOG2E);
    float s11 = __builtin_amdgcn_exp2f((e11 - mx1) * LOG2E);
    float sm0 = s00 + s01, sm1 = s10 + s11;
    for (int m = 32; m; m >>= 1) {
        sm0 += __shfl_xor(sm0, m);
        sm1 += __shfl_xor(sm1, m);
    }
    if (lane == 0) { wred[0][wv] = sm0; wred[1][wv] = sm1; }
    __syncthreads();
    sm0 = 0.f; sm1 = 0.f;
    #pragma unroll
    for (int i = 0; i < 8; ++i) { sm0 += wred[0][i]; sm1 += wred[1][i]; }
    float r0 = __builtin_amdgcn_rcpf(sm0);
    float r1 = __builtin_amdgcn_rcpf(sm1);
    float2 o0; o0.x = s00 * r0; o0.y = s01 * r0;
    float2 o1; o1.x = s10 * r1; o1.y = s11 * r1;
    ((float2*)(out + (size_t)(ny + 0) * 1024))[t] = o0;
    ((float2*)(out + (size_t)(ny + 1) * 1024))[t] = o1;
}

// ----------------------------------------------------------------- launcher
extern "C" void kernel_launch(void* const* d_in, const int* in_sizes, int n_in,
                              void* d_out, int out_size, void* d_ws, size_t ws_size,
                              hipStream_t stream) {
    const float* h  = (const float*)d_in[0];
    const float* s  = (const float*)d_in[1];
    const float* Wh = (const float*)d_in[2];
    const float* Ws = (const float*)d_in[3];
    const float* b  = (const float*)d_in[4];
    const float* v  = (const float*)d_in[5];
    float* out = (float*)d_out;

    char* ws = (char*)d_ws;
    float*  Eph = (float*)ws;                                  // 4 MB
    float*  Eps = (float*)(ws + (4u << 20));                   // 512 KB
    __bf16* WhT = (__bf16*)(ws + (4u << 20) + (512u << 10));   // 128 KB
    __bf16* WsT = WhT + (size_t)128 * 512;                     // 256 KB

    transpose_cast<<<24, 256, 0, stream>>>(Wh, Ws, WhT, WsT);
    gemm_fused<<<288, 256, 0, stream>>>(WhT, WsT, h, s, Eph, Eps, b);
    attn_softmax<<<512, 512, 0, stream>>>(Eph, Eps, v, out);
}